// Round 6
// baseline (1105.868 us; speedup 1.0000x reference)
//
#include <hip/hip_runtime.h>
#include <hip/hip_bf16.h>

// Problem constants (B=4, H=16, S=2048, D=64, fp32).
#define S_LEN 2048
#define DK    64
#define KT    64                   // number of 32-wide k-tiles
#define O_ELEMS (4 * 16 * 2048 * 64)       // 8388608 = B*H*S*D

typedef float f32x4  __attribute__((ext_vector_type(4)));
typedef short bf16x8 __attribute__((ext_vector_type(8)));

static __device__ __forceinline__ unsigned short f2bf(float f) {
  unsigned int u = __builtin_bit_cast(unsigned int, f);
  u += 0x7fffu + ((u >> 16) & 1u);
  return (unsigned short)(u >> 16);
}
static __device__ __forceinline__ float bf2f(unsigned short h) {
  unsigned int u = ((unsigned int)h) << 16;
  return __builtin_bit_cast(float, u);
}

// async global->LDS, 16B per lane; LDS dest = wave-uniform base + lane*16
static __device__ __forceinline__ void gload_lds16(const void* g, void* l) {
  __builtin_amdgcn_global_load_lds(
      (const __attribute__((address_space(1))) unsigned int*)g,
      (__attribute__((address_space(3))) unsigned int*)l, 16, 0, 0);
}

// ---------------------------------------------------------------------------
// K -> (K_hi, K_lo) bf16 split. Same [B,H,S,D] layout. grid 8192 x 256.
__global__ __launch_bounds__(256) void cvt_k_kernel(
    const float* __restrict__ k,
    unsigned short* __restrict__ k_hi,
    unsigned short* __restrict__ k_lo) {
  int i = blockIdx.x * 256 + threadIdx.x;
  float4 v = ((const float4*)k)[i];
  ushort4 h, l;
  h.x = f2bf(v.x); l.x = f2bf(v.x - bf2f(h.x));
  h.y = f2bf(v.y); l.y = f2bf(v.y - bf2f(h.y));
  h.z = f2bf(v.z); l.z = f2bf(v.z - bf2f(h.z));
  h.w = f2bf(v.w); l.w = f2bf(v.w - bf2f(h.w));
  ((ushort4*)k_hi)[i] = h;
  ((ushort4*)k_lo)[i] = l;
}

// ---------------------------------------------------------------------------
// V [bh][j][d] fp32 -> V_t [bh][d][j] bf16. grid 2048.
__global__ __launch_bounds__(256) void transpose_v_kernel(
    const float* __restrict__ v,
    unsigned short* __restrict__ v_t) {
  __shared__ float tile[64][65];
  const int b  = blockIdx.x;
  const int bh = b >> 5;
  const int j0 = (b & 31) << 6;
  const int t  = threadIdx.x;
  #pragma unroll
  for (int i = 0; i < 4; ++i) {
    int flat = i * 256 + t;
    int jl   = flat >> 4;
    int f4   = flat & 15;
    float4 x = *(const float4*)(v + ((size_t)bh * S_LEN + j0 + jl) * DK + f4 * 4);
    tile[jl][f4 * 4 + 0] = x.x;
    tile[jl][f4 * 4 + 1] = x.y;
    tile[jl][f4 * 4 + 2] = x.z;
    tile[jl][f4 * 4 + 3] = x.w;
  }
  __syncthreads();
  #pragma unroll
  for (int i = 0; i < 4; ++i) {
    int flat = i * 256 + t;
    int d    = flat >> 4;
    int jg   = (flat & 15) << 2;
    ushort4 o;
    o.x = f2bf(tile[jg + 0][d]);
    o.y = f2bf(tile[jg + 1][d]);
    o.z = f2bf(tile[jg + 2][d]);
    o.w = f2bf(tile[jg + 3][d]);
    *(ushort4*)(v_t + ((size_t)bh * DK + d) * S_LEN + j0 + jg) = o;
  }
}

// ---------------------------------------------------------------------------
// mask int32 [row][2048 cols] -> transposed bit layout:
// bitsT[(row*16 + c)*4 + w], bit b of word w = mask[row][c + 16*(32w+b)].
// A thread in attn with c=l15 then gets bit (s,t) at word t>>4, bit 2(t&15)+s.
// Block = 32 rows; phase 1 packs linear bits into LDS, phase 2 transposes.
__global__ __launch_bounds__(256) void pack_mask_t_kernel(
    const int* __restrict__ mask,
    unsigned int* __restrict__ bitsT) {
  __shared__ unsigned int lin[32][64];
  const size_t row0 = (size_t)blockIdx.x * 32;   // grid 4096
  const int t = threadIdx.x;
  // phase 1: thread packs 8 consecutive 32-col words of one row
  {
    const int r  = t >> 3;             // 0..31
    const int wg = t & 7;              // words wg*8 .. wg*8+7
    const int* src = mask + (row0 + r) * 2048 + wg * 256;
    #pragma unroll
    for (int wi = 0; wi < 8; ++wi) {
      unsigned int b = 0;
      const int4* mp = (const int4*)(src + wi * 32);
      #pragma unroll
      for (int i = 0; i < 8; ++i) {
        int4 m = mp[i];
        b |= (unsigned)(m.x != 0) << (i * 4 + 0);
        b |= (unsigned)(m.y != 0) << (i * 4 + 1);
        b |= (unsigned)(m.z != 0) << (i * 4 + 2);
        b |= (unsigned)(m.w != 0) << (i * 4 + 3);
      }
      lin[r][wg * 8 + wi] = b;
    }
  }
  __syncthreads();
  // phase 2: bit transpose; thread handles 2 (row,c) pairs, 4 words each
  #pragma unroll
  for (int p2 = 0; p2 < 2; ++p2) {
    const int p = p2 * 256 + t;        // 0..511
    const int r = p >> 4;              // 0..31
    const int c = p & 15;              // 0..15
    unsigned int o[4];
    #pragma unroll
    for (int wo = 0; wo < 4; ++wo) {
      unsigned int acc = 0;
      #pragma unroll
      for (int bp = 0; bp < 16; ++bp) {
        const unsigned int lw = lin[r][16 * wo + bp];   // broadcast across c
        acc |= ((lw >> c) & 1u) << (2 * bp);
        acc |= ((lw >> (16 + c)) & 1u) << (2 * bp + 1);
      }
      o[wo] = acc;
    }
    *(uint4*)(bitsT + ((row0 + r) * 16 + c) * 4) = make_uint4(o[0], o[1], o[2], o[3]);
  }
}

// ---------------------------------------------------------------------------
// Fused attention. Block = 64 q-rows of one (b,h); 4 waves x 16 rows.
// KVBLK=32 tiles, triple-buffered LDS, 2-ahead prefetch, exact counted vmcnt.
// NO per-iteration VM loads (mask bits live in 16 VGPRs) -> stores never
// block the pipeline (in-order vmcnt counting, derived in journal R6).
__global__ __launch_bounds__(256, 4) void attn_main(
    const float* __restrict__ q,
    const unsigned int* __restrict__ bitsT,
    const unsigned short* __restrict__ k_hi,
    const unsigned short* __restrict__ k_lo,
    const unsigned short* __restrict__ v_t,
    float* __restrict__ out_o,
    float* __restrict__ out_w) {
  const int blk = blockIdx.x;                 // 0..2047
  const int id  = ((blk & 7) << 8) | (blk >> 3);  // XCD-contig bh ranges
  const int bh  = id >> 5;                    // 0..63
  const int q0  = (id & 31) << 6;             // q-tile * 64

  const int tid = threadIdx.x;
  const int w   = tid >> 6;                   // wave 0..3
  const int ln  = tid & 63;
  const int l15 = ln & 15;
  const int lq  = ln >> 4;                    // 0..3

  __shared__ __align__(16) unsigned short kh_s[3][32][64];  // 12 KB
  __shared__ __align__(16) unsigned short kl_s[3][32][64];  // 12 KB
  __shared__ __align__(16) unsigned short vt_s[3][64][32];  // 12 KB
  __shared__ __align__(16) unsigned short p_lds[4][16][32]; //  4 KB (swizzled)

  // ---- staging source addressing (swizzle at the source, rule #21) ----
  const int r8 = ln >> 3, c8 = ln & 7;
  const size_t kst = ((size_t)bh * S_LEN + 8 * w + r8) * DK + ((size_t)(c8 ^ r8) << 3);
  const int r4 = ln >> 2;
  const size_t vst = ((size_t)bh * DK + 16 * w + r4) * S_LEN +
                     ((size_t)((ln & 3) ^ ((ln >> 3) & 3)) << 3);

  auto stage_K = [&](int t, int b) {
    gload_lds16(k_hi + kst + (size_t)t * (32 * DK), &kh_s[b][8 * w][0]);
    gload_lds16(k_lo + kst + (size_t)t * (32 * DK), &kl_s[b][8 * w][0]);
  };
  auto stage_V = [&](int t, int b) {
    gload_lds16(v_t + vst + (size_t)t * 32, &vt_s[b][16 * w][0]);
  };

  // Q + mask loads issued BEFORE staging (older than all DMA -> never block it)
  const float* qp = q + ((size_t)bh * S_LEN + q0 + (w << 4) + l15) * DK + (lq << 3);
  const float4 qa0 = *(const float4*)(qp);
  const float4 qb0 = *(const float4*)(qp + 4);
  const float4 qa1 = *(const float4*)(qp + 32);
  const float4 qb1 = *(const float4*)(qp + 36);

  const size_t rowb = (size_t)bh * S_LEN + q0 + (w << 4) + (lq << 2);
  uint4 mw[4];
  #pragma unroll
  for (int r = 0; r < 4; ++r)
    mw[r] = *(const uint4*)(bitsT + ((rowb + r) * 16 + l15) * 4);

  stage_K(0, 0);
  stage_K(1, 1);

  // ---- Q A-fragments: scale by log2(e)/8, split hi/lo ----
  bf16x8 qh[2], ql[2];
  {
    const float sc = 0.125f * 1.4426950408889634f;
    float vv0[8] = {qa0.x, qa0.y, qa0.z, qa0.w, qb0.x, qb0.y, qb0.z, qb0.w};
    float vv1[8] = {qa1.x, qa1.y, qa1.z, qa1.w, qb1.x, qb1.y, qb1.z, qb1.w};
    #pragma unroll
    for (int i = 0; i < 8; ++i) {
      float s0 = vv0[i] * sc;
      unsigned short h0 = f2bf(s0);
      qh[0][i] = (short)h0; ql[0][i] = (short)f2bf(s0 - bf2f(h0));
      float s1 = vv1[i] * sc;
      unsigned short h1 = f2bf(s1);
      qh[1][i] = (short)h1; ql[1][i] = (short)f2bf(s1 - bf2f(h1));
    }
  }

  const size_t mofs = rowb * S_LEN + l15;     // weights offset
  const size_t oofs = rowb * DK + l15;

  auto qk_tile = [&](int b, f32x4 (&acc)[2]) {
    #pragma unroll
    for (int s = 0; s < 2; ++s) {
      #pragma unroll
      for (int c = 0; c < 2; ++c) {
        const int off = (s * 16 + l15) * 64 + ((((c << 2) | lq) ^ (l15 & 7)) << 3);
        const bf16x8 bhf = *(const bf16x8*)(&kh_s[b][0][0] + off);
        const bf16x8 blf = *(const bf16x8*)(&kl_s[b][0][0] + off);
        acc[s] = __builtin_amdgcn_mfma_f32_16x16x32_bf16(ql[c], bhf, acc[s], 0, 0, 0);
        acc[s] = __builtin_amdgcn_mfma_f32_16x16x32_bf16(qh[c], blf, acc[s], 0, 0, 0);
        acc[s] = __builtin_amdgcn_mfma_f32_16x16x32_bf16(qh[c], bhf, acc[s], 0, 0, 0);
      }
    }
  };

  float sums[4] = {0.f, 0.f, 0.f, 0.f};

// ---- pass A body. WAITN: #VM ops younger than stage(T) (see journal R6) ----
#define PA_BODY(T, WAITN)                                                    \
  {                                                                          \
    asm volatile("s_waitcnt vmcnt(" #WAITN ")" ::: "memory");                \
    __builtin_amdgcn_s_barrier();                                            \
    __builtin_amdgcn_sched_barrier(0);                                       \
    const int b_ = (T) % 3;                                                  \
    if ((T) + 2 < KT) stage_K((T) + 2, ((T) + 2) % 3);                       \
    f32x4 acc[2];                                                            \
    acc[0] = f32x4{0.f, 0.f, 0.f, 0.f};                                      \
    acc[1] = f32x4{0.f, 0.f, 0.f, 0.f};                                      \
    qk_tile(b_, acc);                                                        \
    const int wsel = (T) >> 4;                                               \
    const int sh0 = 2 * ((T) & 15);                                          \
    _Pragma("unroll") for (int s = 0; s < 2; ++s) {                          \
      _Pragma("unroll") for (int r = 0; r < 4; ++r) {                        \
        const unsigned mword = wsel == 0 ? mw[r].x : wsel == 1 ? mw[r].y     \
                             : wsel == 2 ? mw[r].z : mw[r].w;                \
        const int m = (int)((mword >> (sh0 + s)) & 1u);                      \
        sums[r] += m ? 0.f : __builtin_amdgcn_exp2f(acc[s][r]);              \
      }                                                                      \
    }                                                                        \
  }

  // steady vmcnt(2) = stage(t+1); last iter drains (no trailing stage)
  for (int t = 0; t < KT - 1; ++t) PA_BODY(t, 2);
  PA_BODY(KT - 1, 0);

  #pragma unroll
  for (int r = 0; r < 4; ++r) {
    float x = sums[r];
    x += __shfl_xor(x, 1, 64);
    x += __shfl_xor(x, 2, 64);
    x += __shfl_xor(x, 4, 64);
    x += __shfl_xor(x, 8, 64);
    sums[r] = 1.0f / x;
  }

  // ---------------- pass B: weights + PV ----------------
  f32x4 oacc[4];
  #pragma unroll
  for (int s = 0; s < 4; ++s) oacc[s] = f32x4{0.f, 0.f, 0.f, 0.f};

  __builtin_amdgcn_s_barrier();               // all pass-A buffer reads done
  __builtin_amdgcn_sched_barrier(0);
  stage_K(0, 0); stage_V(0, 0);
  stage_K(1, 1); stage_V(1, 1);

#define PB_BODY(T, WAITN)                                                    \
  {                                                                          \
    asm volatile("s_waitcnt vmcnt(" #WAITN ")" ::: "memory");                \
    __builtin_amdgcn_s_barrier();                                            \
    __builtin_amdgcn_sched_barrier(0);                                       \
    const int b_ = (T) % 3;                                                  \
    if ((T) + 2 < KT) { stage_K((T) + 2, ((T) + 2) % 3);                     \
                        stage_V((T) + 2, ((T) + 2) % 3); }                   \
    f32x4 acc[2];                                                            \
    acc[0] = f32x4{0.f, 0.f, 0.f, 0.f};                                      \
    acc[1] = f32x4{0.f, 0.f, 0.f, 0.f};                                      \
    qk_tile(b_, acc);                                                        \
    const int wsel = (T) >> 4;                                               \
    const int sh0 = 2 * ((T) & 15);                                          \
    _Pragma("unroll") for (int s = 0; s < 2; ++s) {                          \
      _Pragma("unroll") for (int r = 0; r < 4; ++r) {                        \
        const unsigned mword = wsel == 0 ? mw[r].x : wsel == 1 ? mw[r].y     \
                             : wsel == 2 ? mw[r].z : mw[r].w;                \
        const int m = (int)((mword >> (sh0 + s)) & 1u);                      \
        const float e = m ? 0.f : __builtin_amdgcn_exp2f(acc[s][r]);         \
        const float wn = e * sums[r];                                        \
        out_w[mofs + (size_t)r * S_LEN + (T) * 32 + s * 16] = wn;            \
        const int row = (lq << 2) + r;                                       \
        const int chunk = ((s << 1) | (l15 >> 3)) ^ ((row >> 1) & 3);        \
        p_lds[w][row][(chunk << 3) | (l15 & 7)] = f2bf(wn);                  \
      }                                                                      \
    }                                                                        \
    __builtin_amdgcn_wave_barrier();                                         \
    const bf16x8 pa =                                                        \
        *(const bf16x8*)&p_lds[w][l15][(lq ^ ((l15 >> 1) & 3)) << 3];        \
    _Pragma("unroll") for (int s = 0; s < 4; ++s) {                          \
      const bf16x8 vb =                                                      \
          *(const bf16x8*)&vt_s[b_][s * 16 + l15][(lq ^ ((l15 >> 1) & 3)) << 3]; \
      oacc[s] = __builtin_amdgcn_mfma_f32_16x16x32_bf16(pa, vb, oacc[s], 0, 0, 0); \
    }                                                                        \
    __builtin_amdgcn_wave_barrier();                                         \
  }

  // waits: t=0 -> stage(1)=3 younger; t=1 -> stores(0)8+stage(2)3=11;
  // steady -> stores(t-2)8+stage(t+1)3+stores(t-1)8=19; last -> drain.
  PB_BODY(0, 3);
  PB_BODY(1, 11);
  for (int t = 2; t < KT - 1; ++t) PB_BODY(t, 19);
  PB_BODY(KT - 1, 0);

  #pragma unroll
  for (int s = 0; s < 4; ++s) {
    #pragma unroll
    for (int r = 0; r < 4; ++r) {
      out_o[oofs + (size_t)r * DK + s * 16] = oacc[s][r];
    }
  }
#undef PA_BODY
#undef PB_BODY
}

// ---------------------------------------------------------------------------
extern "C" void kernel_launch(void* const* d_in, const int* in_sizes, int n_in,
                              void* d_out, int out_size, void* d_ws, size_t ws_size,
                              hipStream_t stream) {
  (void)in_sizes; (void)n_in; (void)out_size; (void)ws_size;
  const float* q = (const float*)d_in[0];
  const float* k = (const float*)d_in[1];
  const float* v = (const float*)d_in[2];
  const int* mask = (const int*)d_in[3];      // bool_ -> int32

  float* out_o = (float*)d_out;               // [B,H,S,D] fp32
  float* out_w = out_o + (size_t)O_ELEMS;     // [B,H,S,S] fp32

  // workspace: K_hi, K_lo, V_t (3 x 16.8 MB) + transposed mask bits (33.6 MB)
  unsigned short* k_hi = (unsigned short*)d_ws;
  unsigned short* k_lo = k_hi + (size_t)O_ELEMS;
  unsigned short* v_t  = k_lo + (size_t)O_ELEMS;
  unsigned int*   bitsT = (unsigned int*)(v_t + (size_t)O_ELEMS);

  cvt_k_kernel<<<O_ELEMS / (256 * 4), 256, 0, stream>>>(k, k_hi, k_lo);
  transpose_v_kernel<<<2048, 256, 0, stream>>>(v, v_t);
  pack_mask_t_kernel<<<4096, 256, 0, stream>>>(mask, bitsT);
  attn_main<<<2048, 256, 0, stream>>>(q, bitsT, k_hi, k_lo, v_t, out_o, out_w);
}

// Round 7
// 731.486 us; speedup vs baseline: 1.5118x; 1.5118x over previous
//
#include <hip/hip_runtime.h>
#include <hip/hip_bf16.h>

// Problem constants (B=4, H=16, S=2048, D=64, fp32).
#define S_LEN 2048
#define DK    64
#define NT64  32                   // number of 64-wide k-tiles
#define O_ELEMS (4 * 16 * 2048 * 64)       // 8388608 = B*H*S*D

typedef float f32x4  __attribute__((ext_vector_type(4)));
typedef short bf16x8 __attribute__((ext_vector_type(8)));

static __device__ __forceinline__ unsigned short f2bf(float f) {
  unsigned int u = __builtin_bit_cast(unsigned int, f);
  u += 0x7fffu + ((u >> 16) & 1u);
  return (unsigned short)(u >> 16);
}

// async global->LDS, 16B per lane; LDS dest = wave-uniform base + lane*16
static __device__ __forceinline__ void gload_lds16(const void* g, void* l) {
  __builtin_amdgcn_global_load_lds(
      (const __attribute__((address_space(1))) unsigned int*)g,
      (__attribute__((address_space(3))) unsigned int*)l, 16, 0, 0);
}

// ---------------------------------------------------------------------------
// K fp32 -> bf16 (plain round-to-nearest; no split). grid 8192 x 256.
__global__ __launch_bounds__(256) void cvt_k_kernel(
    const float* __restrict__ k, unsigned short* __restrict__ k_hi) {
  int i = blockIdx.x * 256 + threadIdx.x;
  float4 v = ((const float4*)k)[i];
  ushort4 h;
  h.x = f2bf(v.x); h.y = f2bf(v.y); h.z = f2bf(v.z); h.w = f2bf(v.w);
  ((ushort4*)k_hi)[i] = h;
}

// ---------------------------------------------------------------------------
// V [bh][j][d] fp32 -> V_t [bh][d][j] bf16. grid 2048.
__global__ __launch_bounds__(256) void transpose_v_kernel(
    const float* __restrict__ v, unsigned short* __restrict__ v_t) {
  __shared__ float tile[64][65];
  const int b  = blockIdx.x;
  const int bh = b >> 5;
  const int j0 = (b & 31) << 6;
  const int t  = threadIdx.x;
  #pragma unroll
  for (int i = 0; i < 4; ++i) {
    int flat = i * 256 + t;
    int jl   = flat >> 4;
    int f4   = flat & 15;
    float4 x = *(const float4*)(v + ((size_t)bh * S_LEN + j0 + jl) * DK + f4 * 4);
    tile[jl][f4 * 4 + 0] = x.x;
    tile[jl][f4 * 4 + 1] = x.y;
    tile[jl][f4 * 4 + 2] = x.z;
    tile[jl][f4 * 4 + 3] = x.w;
  }
  __syncthreads();
  #pragma unroll
  for (int i = 0; i < 4; ++i) {
    int flat = i * 256 + t;
    int d    = flat >> 4;
    int jg   = (flat & 15) << 2;
    ushort4 o;
    o.x = f2bf(tile[jg + 0][d]);
    o.y = f2bf(tile[jg + 1][d]);
    o.z = f2bf(tile[jg + 2][d]);
    o.w = f2bf(tile[jg + 3][d]);
    *(ushort4*)(v_t + ((size_t)bh * DK + d) * S_LEN + j0 + jg) = o;
  }
}

// ---------------------------------------------------------------------------
// mask int32 [row][2048] -> transposed bits: bitsT[(row*16+c)*4 + w], bit b of
// word w = mask[row][16*(32w+b)+c].  Phase-1 access pattern: each wave
// iteration covers 64 consecutive 32-int chunks = 8KB contiguous (L1-friendly;
// R6's 64KB-per-wave footprint thrashed the 32KB L1 -> 2x slowdown).
__global__ __launch_bounds__(256) void pack_mask_t_kernel(
    const int* __restrict__ mask, unsigned int* __restrict__ bitsT) {
  __shared__ unsigned int lin[32][64];
  const size_t row0 = (size_t)blockIdx.x * 32;   // grid 4096
  const int t = threadIdx.x;
  #pragma unroll
  for (int p = 0; p < 8; ++p) {
    const int chunk = p * 256 + t;               // 0..2047 (32 rows x 64 words)
    const int4* mp = (const int4*)(mask + row0 * 2048 + (size_t)chunk * 32);
    unsigned int b = 0;
    #pragma unroll
    for (int i = 0; i < 8; ++i) {
      int4 m = mp[i];
      b |= (unsigned)(m.x != 0) << (i * 4 + 0);
      b |= (unsigned)(m.y != 0) << (i * 4 + 1);
      b |= (unsigned)(m.z != 0) << (i * 4 + 2);
      b |= (unsigned)(m.w != 0) << (i * 4 + 3);
    }
    lin[chunk >> 6][chunk & 63] = b;
  }
  __syncthreads();
  #pragma unroll
  for (int p2 = 0; p2 < 2; ++p2) {
    const int p = p2 * 256 + t;                  // 0..511
    const int r = p >> 4;
    const int c = p & 15;
    unsigned int o[4];
    #pragma unroll
    for (int wo = 0; wo < 4; ++wo) {
      unsigned int acc = 0;
      #pragma unroll
      for (int bp = 0; bp < 16; ++bp) {
        const unsigned int lw = lin[r][16 * wo + bp];   // broadcast across c
        acc |= ((lw >> c) & 1u) << (2 * bp);
        acc |= ((lw >> (16 + c)) & 1u) << (2 * bp + 1);
      }
      o[wo] = acc;
    }
    *(uint4*)(bitsT + ((row0 + r) * 16 + c) * 4) = make_uint4(o[0], o[1], o[2], o[3]);
  }
}

// ---------------------------------------------------------------------------
// Fused attention. Block = 64 q-rows of one (b,h); 4 waves x 16 rows.
// KVBLK=64 tiles (32 iters/pass), double-buffered LDS (40KB -> 4 blocks/CU),
// wait-BEFORE-issue counted vmcnt: pass A vmcnt(0) [nothing else in flight],
// pass B vmcnt(16) [stores(t-1)=16 youngest allowed; stage(t) must retire].
// Plain bf16 QK^T (no hi/lo split; error budget verified vs 1.56e-2 threshold).
__global__ __launch_bounds__(256, 4) void attn_main(
    const float* __restrict__ q,
    const unsigned int* __restrict__ bitsT,
    const unsigned short* __restrict__ k_hi,
    const unsigned short* __restrict__ v_t,
    float* __restrict__ out_o,
    float* __restrict__ out_w) {
  const int blk = blockIdx.x;                 // 0..2047
  const int id  = ((blk & 7) << 8) | (blk >> 3);  // XCD-contig bh ranges
  const int bh  = id >> 5;                    // 0..63
  const int q0  = (id & 31) << 6;             // q-tile * 64

  const int tid = threadIdx.x;
  const int w   = tid >> 6;                   // wave 0..3
  const int ln  = tid & 63;
  const int l15 = ln & 15;
  const int lq  = ln >> 4;                    // 0..3

  __shared__ __align__(16) unsigned short kh_s[2][64][64];  // 16 KB
  __shared__ __align__(16) unsigned short vt_s[2][64][64];  // 16 KB
  __shared__ __align__(16) unsigned short p_lds[4][16][64]; //  8 KB (swizzled)

  // ---- staging source addressing (swizzle at the source, rule #21) ----
  // wave stages rows [16w,16w+16) via 2 gloads of 8 rows each.
  const int r8  = ln >> 3, c8 = ln & 7;
  const int swz = c8 ^ r8;                    // source chunk (row&7 == r8)
  const size_t kst = ((size_t)bh * S_LEN + 16 * w + r8) * DK + ((size_t)swz << 3);
  const size_t vst = ((size_t)bh * DK + 16 * w + r8) * S_LEN + ((size_t)swz << 3);

  auto stage_K = [&](int t, int b) {
    gload_lds16(k_hi + kst + (size_t)t * (64 * DK),          &kh_s[b][16 * w][0]);
    gload_lds16(k_hi + kst + (size_t)t * (64 * DK) + 8 * DK, &kh_s[b][16 * w + 8][0]);
  };
  auto stage_V = [&](int t, int b) {
    gload_lds16(v_t + vst + (size_t)t * 64,             &vt_s[b][16 * w][0]);
    gload_lds16(v_t + vst + (size_t)t * 64 + 8 * S_LEN, &vt_s[b][16 * w + 8][0]);
  };

  // Q + mask loads issued BEFORE staging (older -> never block the DMA)
  const float* qp = q + ((size_t)bh * S_LEN + q0 + (w << 4) + l15) * DK + (lq << 3);
  const float4 qa0 = *(const float4*)(qp);
  const float4 qb0 = *(const float4*)(qp + 4);
  const float4 qa1 = *(const float4*)(qp + 32);
  const float4 qb1 = *(const float4*)(qp + 36);
  const size_t rowb = (size_t)bh * S_LEN + q0 + (w << 4) + (lq << 2);
  uint4 mw[4];
  #pragma unroll
  for (int r = 0; r < 4; ++r)
    mw[r] = *(const uint4*)(bitsT + ((rowb + r) * 16 + l15) * 4);

  stage_K(0, 0);

  // ---- Q A-fragments: scale by log2(e)/8 folded in ----
  bf16x8 qh[2];
  {
    const float sc = 0.125f * 1.4426950408889634f;
    float vv0[8] = {qa0.x, qa0.y, qa0.z, qa0.w, qb0.x, qb0.y, qb0.z, qb0.w};
    float vv1[8] = {qa1.x, qa1.y, qa1.z, qa1.w, qb1.x, qb1.y, qb1.z, qb1.w};
    #pragma unroll
    for (int i = 0; i < 8; ++i) {
      qh[0][i] = (short)f2bf(vv0[i] * sc);
      qh[1][i] = (short)f2bf(vv1[i] * sc);
    }
  }

  const size_t mofs = rowb * S_LEN + l15;     // weights offset
  const size_t oofs = rowb * DK + l15;

  // QK subtile: rows j = s*16+l15, k-chunk c -> LDS chunk ((c<<2)|lq)^(l15&7)
  auto qk_tile = [&](const unsigned short* kbase, f32x4 (&acc)[4]) {
    #pragma unroll
    for (int s = 0; s < 4; ++s) {
      #pragma unroll
      for (int c = 0; c < 2; ++c) {
        const int off = (s * 16 + l15) * 64 + ((((c << 2) | lq) ^ (l15 & 7)) << 3);
        const bf16x8 bhf = *(const bf16x8*)(kbase + off);
        acc[s] = __builtin_amdgcn_mfma_f32_16x16x32_bf16(qh[c], bhf, acc[s], 0, 0, 0);
      }
    }
  };

  float sums[4] = {0.f, 0.f, 0.f, 0.f};

// ---- pass A body: wait vmcnt(0) (only stage(T) can be in flight here) ----
#define PA_BODY(T, BUF)                                                      \
  {                                                                          \
    asm volatile("s_waitcnt vmcnt(0)" ::: "memory");                         \
    __builtin_amdgcn_s_barrier();                                            \
    __builtin_amdgcn_sched_barrier(0);                                       \
    if ((T) + 1 < NT64) stage_K((T) + 1, (BUF) ^ 1);                         \
    f32x4 acc[4];                                                            \
    acc[0] = f32x4{0.f, 0.f, 0.f, 0.f}; acc[1] = f32x4{0.f, 0.f, 0.f, 0.f};  \
    acc[2] = f32x4{0.f, 0.f, 0.f, 0.f}; acc[3] = f32x4{0.f, 0.f, 0.f, 0.f};  \
    qk_tile(&kh_s[BUF][0][0], acc);                                          \
    const int wsel = (T) >> 3;                                               \
    const int sh0 = 4 * ((T) & 7);                                           \
    _Pragma("unroll") for (int r = 0; r < 4; ++r) {                          \
      const unsigned mword = wsel == 0 ? mw[r].x : wsel == 1 ? mw[r].y       \
                           : wsel == 2 ? mw[r].z : mw[r].w;                  \
      _Pragma("unroll") for (int s = 0; s < 4; ++s) {                        \
        const int m = (int)((mword >> (sh0 + s)) & 1u);                      \
        sums[r] += m ? 0.f : __builtin_amdgcn_exp2f(acc[s][r]);              \
      }                                                                      \
    }                                                                        \
  }

  PA_BODY(0, 0);
  for (int tt = 0; tt < 15; ++tt) {
    PA_BODY(2 * tt + 1, 1);
    PA_BODY(2 * tt + 2, 0);
  }
  PA_BODY(31, 1);

  #pragma unroll
  for (int r = 0; r < 4; ++r) {
    float x = sums[r];
    x += __shfl_xor(x, 1, 64);
    x += __shfl_xor(x, 2, 64);
    x += __shfl_xor(x, 4, 64);
    x += __shfl_xor(x, 8, 64);
    sums[r] = 1.0f / x;
  }

  // ---------------- pass B: weights + PV ----------------
  f32x4 oacc[4];
  #pragma unroll
  for (int s = 0; s < 4; ++s) oacc[s] = f32x4{0.f, 0.f, 0.f, 0.f};

  // prologue: safe vs stragglers (buf0's last pass-A reads were fenced by
  // the PA(31) barrier; vt buf0 never read before).
  stage_K(0, 0);
  stage_V(0, 0);

#define PB_BODY(T, BUF, WAITN)                                               \
  {                                                                          \
    asm volatile("s_waitcnt vmcnt(" #WAITN ")" ::: "memory");                \
    __builtin_amdgcn_s_barrier();                                            \
    __builtin_amdgcn_sched_barrier(0);                                       \
    if ((T) + 1 < NT64) { stage_K((T) + 1, (BUF) ^ 1);                       \
                          stage_V((T) + 1, (BUF) ^ 1); }                     \
    f32x4 acc[4];                                                            \
    acc[0] = f32x4{0.f, 0.f, 0.f, 0.f}; acc[1] = f32x4{0.f, 0.f, 0.f, 0.f};  \
    acc[2] = f32x4{0.f, 0.f, 0.f, 0.f}; acc[3] = f32x4{0.f, 0.f, 0.f, 0.f};  \
    qk_tile(&kh_s[BUF][0][0], acc);                                          \
    const int wsel = (T) >> 3;                                               \
    const int sh0 = 4 * ((T) & 7);                                           \
    float* wbase = out_w + mofs + (size_t)(T) * 64;                          \
    _Pragma("unroll") for (int r = 0; r < 4; ++r) {                          \
      const unsigned mword = wsel == 0 ? mw[r].x : wsel == 1 ? mw[r].y       \
                           : wsel == 2 ? mw[r].z : mw[r].w;                  \
      const int row = (lq << 2) + r;                                         \
      _Pragma("unroll") for (int s = 0; s < 4; ++s) {                        \
        const int m = (int)((mword >> (sh0 + s)) & 1u);                      \
        const float e = m ? 0.f : __builtin_amdgcn_exp2f(acc[s][r]);         \
        const float wn = e * sums[r];                                        \
        wbase[(size_t)r * S_LEN + s * 16] = wn;                              \
        const int chunk = ((s << 1) | (l15 >> 3)) ^ (row & 7);               \
        p_lds[w][row][(chunk << 3) | (l15 & 7)] = f2bf(wn);                  \
      }                                                                      \
    }                                                                        \
    __builtin_amdgcn_wave_barrier();                                         \
    _Pragma("unroll") for (int c = 0; c < 2; ++c) {                          \
      const bf16x8 pa = *(const bf16x8*)                                     \
          &p_lds[w][l15][((((c << 2) | lq)) ^ (l15 & 7)) << 3];              \
      _Pragma("unroll") for (int s = 0; s < 4; ++s) {                        \
        const int off = (s * 16 + l15) * 64 +                                \
                        ((((c << 2) | lq) ^ (l15 & 7)) << 3);                \
        const bf16x8 vb = *(const bf16x8*)(&vt_s[BUF][0][0] + off);          \
        oacc[s] = __builtin_amdgcn_mfma_f32_16x16x32_bf16(pa, vb, oacc[s],   \
                                                          0, 0, 0);          \
      }                                                                      \
    }                                                                        \
    __builtin_amdgcn_wave_barrier();                                         \
  }

  PB_BODY(0, 0, 0);
  for (int tt = 0; tt < 15; ++tt) {
    PB_BODY(2 * tt + 1, 1, 16);
    PB_BODY(2 * tt + 2, 0, 16);
  }
  PB_BODY(31, 1, 16);

  #pragma unroll
  for (int s = 0; s < 4; ++s) {
    #pragma unroll
    for (int r = 0; r < 4; ++r) {
      out_o[oofs + (size_t)r * DK + s * 16] = oacc[s][r];
    }
  }
#undef PA_BODY
#undef PB_BODY
}

// ---------------------------------------------------------------------------
extern "C" void kernel_launch(void* const* d_in, const int* in_sizes, int n_in,
                              void* d_out, int out_size, void* d_ws, size_t ws_size,
                              hipStream_t stream) {
  (void)in_sizes; (void)n_in; (void)out_size; (void)ws_size;
  const float* q = (const float*)d_in[0];
  const float* k = (const float*)d_in[1];
  const float* v = (const float*)d_in[2];
  const int* mask = (const int*)d_in[3];      // bool_ -> int32

  float* out_o = (float*)d_out;               // [B,H,S,D] fp32
  float* out_w = out_o + (size_t)O_ELEMS;     // [B,H,S,S] fp32

  // workspace: K bf16 (16.8 MB) + V_t bf16 (16.8 MB) + bitsT (33.6 MB)
  unsigned short* k_hi = (unsigned short*)d_ws;
  unsigned short* v_t  = k_hi + (size_t)O_ELEMS;
  unsigned int*   bitsT = (unsigned int*)(v_t + (size_t)O_ELEMS);

  cvt_k_kernel<<<8192, 256, 0, stream>>>(k, k_hi);
  transpose_v_kernel<<<2048, 256, 0, stream>>>(v, v_t);
  pack_mask_t_kernel<<<4096, 256, 0, stream>>>(mask, bitsT);
  attn_main<<<2048, 256, 0, stream>>>(q, bitsT, k_hi, v_t, out_o, out_w);
}

// Round 8
// 665.358 us; speedup vs baseline: 1.6621x; 1.0994x over previous
//
#include <hip/hip_runtime.h>
#include <hip/hip_bf16.h>

// Problem constants (B=4, H=16, S=2048, D=64, fp32).
#define S_LEN 2048
#define DK    64
#define NT64  32                   // number of 64-wide k-tiles
#define O_ELEMS (4 * 16 * 2048 * 64)       // 8388608 = B*H*S*D

typedef float f32x4  __attribute__((ext_vector_type(4)));
typedef short bf16x8 __attribute__((ext_vector_type(8)));

static __device__ __forceinline__ unsigned short f2bf(float f) {
  unsigned int u = __builtin_bit_cast(unsigned int, f);
  u += 0x7fffu + ((u >> 16) & 1u);
  return (unsigned short)(u >> 16);
}

// async global->LDS, 16B per lane; LDS dest = wave-uniform base + lane*16
static __device__ __forceinline__ void gload_lds16(const void* g, void* l) {
  __builtin_amdgcn_global_load_lds(
      (const __attribute__((address_space(1))) unsigned int*)g,
      (__attribute__((address_space(3))) unsigned int*)l, 16, 0, 0);
}

// ---------------------------------------------------------------------------
// K fp32 -> bf16 (plain round-to-nearest). grid 8192 x 256.
__global__ __launch_bounds__(256) void cvt_k_kernel(
    const float* __restrict__ k, unsigned short* __restrict__ k_hi) {
  int i = blockIdx.x * 256 + threadIdx.x;
  float4 v = ((const float4*)k)[i];
  ushort4 h;
  h.x = f2bf(v.x); h.y = f2bf(v.y); h.z = f2bf(v.z); h.w = f2bf(v.w);
  ((ushort4*)k_hi)[i] = h;
}

// ---------------------------------------------------------------------------
// V [bh][j][d] fp32 -> V_t [bh][d][j] bf16. grid 2048.
__global__ __launch_bounds__(256) void transpose_v_kernel(
    const float* __restrict__ v, unsigned short* __restrict__ v_t) {
  __shared__ float tile[64][65];
  const int b  = blockIdx.x;
  const int bh = b >> 5;
  const int j0 = (b & 31) << 6;
  const int t  = threadIdx.x;
  #pragma unroll
  for (int i = 0; i < 4; ++i) {
    int flat = i * 256 + t;
    int jl   = flat >> 4;
    int f4   = flat & 15;
    float4 x = *(const float4*)(v + ((size_t)bh * S_LEN + j0 + jl) * DK + f4 * 4);
    tile[jl][f4 * 4 + 0] = x.x;
    tile[jl][f4 * 4 + 1] = x.y;
    tile[jl][f4 * 4 + 2] = x.z;
    tile[jl][f4 * 4 + 3] = x.w;
  }
  __syncthreads();
  #pragma unroll
  for (int i = 0; i < 4; ++i) {
    int flat = i * 256 + t;
    int d    = flat >> 4;
    int jg   = (flat & 15) << 2;
    ushort4 o;
    o.x = f2bf(tile[jg + 0][d]);
    o.y = f2bf(tile[jg + 1][d]);
    o.z = f2bf(tile[jg + 2][d]);
    o.w = f2bf(tile[jg + 3][d]);
    *(ushort4*)(v_t + ((size_t)bh * DK + d) * S_LEN + j0 + jg) = o;
  }
}

// ---------------------------------------------------------------------------
// Fused attention, mask streamed in-kernel (no pack kernel, no bitsT).
// Block = 64 q-rows of one (b,h); 4 waves x 16 rows. KVBLK=64 (32 iters/pass).
// Pass A: stage mask int32 tile (16KB) 1-ahead double-buffered; use for sums
//         AND pack bits into mwv[4][4] registers (all-static indices).
// Pass B: identical to R7 (mask from registers), vmcnt(16) steady.
// LDS 72KB -> 2 blocks/CU. vmcnt derivation in journal R8:
//   PA top vmcnt(4)  [K(t) retired; M(t)'s 4 may fly]
//   PA mid vmcnt(6)  [M(t) retired; K/M(t+1)'s 6 may fly]  (last iter: 0)
//   PB top vmcnt(16) [K/V(t) retired; stores(t-1) may fly] (t=0: 0)
__global__ __launch_bounds__(256, 2) void attn_main(
    const float* __restrict__ q,
    const int* __restrict__ mask,
    const unsigned short* __restrict__ k_hi,
    const unsigned short* __restrict__ v_t,
    float* __restrict__ out_o,
    float* __restrict__ out_w) {
  const int blk = blockIdx.x;                 // 0..2047
  const int id  = ((blk & 7) << 8) | (blk >> 3);  // XCD-contig bh ranges
  const int bh  = id >> 5;                    // 0..63
  const int q0  = (id & 31) << 6;             // q-tile * 64

  const int tid = threadIdx.x;
  const int w   = tid >> 6;                   // wave 0..3
  const int ln  = tid & 63;
  const int l15 = ln & 15;
  const int lq  = ln >> 4;                    // 0..3

  __shared__ __align__(16) unsigned short kh_s[2][64][64];  // 16 KB
  __shared__ __align__(16) unsigned short vt_s[2][64][64];  // 16 KB
  __shared__ __align__(16) int            m_lds[2][64][64]; // 32 KB
  __shared__ __align__(16) unsigned short p_lds[4][16][64]; //  8 KB (swizzled)

  // ---- staging source addressing (swizzle at the source, rule #21) ----
  const int r8  = ln >> 3, c8 = ln & 7;
  const int swz = c8 ^ r8;
  const size_t kst = ((size_t)bh * S_LEN + 16 * w + r8) * DK + ((size_t)swz << 3);
  const size_t vst = ((size_t)bh * DK + 16 * w + r8) * S_LEN + ((size_t)swz << 3);
  // mask source: lane -> row 16w+4u+(ln>>4), int4 chunk ln&15 (linear, no swz)
  const int* mbase = mask + ((size_t)bh * S_LEN + q0 + 16 * w + (ln >> 4)) * S_LEN
                          + ((ln & 15) << 2);

  auto stage_K = [&](int t, int b) {
    gload_lds16(k_hi + kst + (size_t)t * (64 * DK),          &kh_s[b][16 * w][0]);
    gload_lds16(k_hi + kst + (size_t)t * (64 * DK) + 8 * DK, &kh_s[b][16 * w + 8][0]);
  };
  auto stage_V = [&](int t, int b) {
    gload_lds16(v_t + vst + (size_t)t * 64,             &vt_s[b][16 * w][0]);
    gload_lds16(v_t + vst + (size_t)t * 64 + 8 * S_LEN, &vt_s[b][16 * w + 8][0]);
  };
  auto stage_M = [&](int t, int b) {
    #pragma unroll
    for (int u = 0; u < 4; ++u) {
      gload_lds16(mbase + (size_t)(4 * u) * S_LEN + t * 64,
                  &m_lds[b][16 * w + 4 * u][0]);
    }
  };

  // Q loads issued BEFORE staging (older -> never block the DMA)
  const float* qp = q + ((size_t)bh * S_LEN + q0 + (w << 4) + l15) * DK + (lq << 3);
  const float4 qa0 = *(const float4*)(qp);
  const float4 qb0 = *(const float4*)(qp + 4);
  const float4 qa1 = *(const float4*)(qp + 32);
  const float4 qb1 = *(const float4*)(qp + 36);

  stage_K(0, 0);     // order matters for vmcnt counts: K first,
  stage_M(0, 0);     // then M (4 ops younger)

  // ---- Q A-fragments: scale by log2(e)/8 folded in ----
  bf16x8 qh[2];
  {
    const float sc = 0.125f * 1.4426950408889634f;
    float vv0[8] = {qa0.x, qa0.y, qa0.z, qa0.w, qb0.x, qb0.y, qb0.z, qb0.w};
    float vv1[8] = {qa1.x, qa1.y, qa1.z, qa1.w, qb1.x, qb1.y, qb1.z, qb1.w};
    #pragma unroll
    for (int i = 0; i < 8; ++i) {
      qh[0][i] = (short)f2bf(vv0[i] * sc);
      qh[1][i] = (short)f2bf(vv1[i] * sc);
    }
  }

  const size_t rowb = (size_t)bh * S_LEN + q0 + (w << 4) + (lq << 2);
  const size_t mofs = rowb * S_LEN + l15;     // weights offset
  const size_t oofs = rowb * DK + l15;
  const int rowblk = (w << 4) + (lq << 2);    // this thread's block-row base

  // QK subtile: rows j = s*16+l15, k-chunk c -> LDS chunk ((c<<2)|lq)^(l15&7)
  auto qk_tile = [&](const unsigned short* kbase, f32x4 (&acc)[4]) {
    #pragma unroll
    for (int s = 0; s < 4; ++s) {
      #pragma unroll
      for (int c = 0; c < 2; ++c) {
        const int off = (s * 16 + l15) * 64 + ((((c << 2) | lq) ^ (l15 & 7)) << 3);
        const bf16x8 bhf = *(const bf16x8*)(kbase + off);
        acc[s] = __builtin_amdgcn_mfma_f32_16x16x32_bf16(qh[c], bhf, acc[s], 0, 0, 0);
      }
    }
  };

  float sums[4] = {0.f, 0.f, 0.f, 0.f};
  unsigned mwv[4][4];                         // packed mask bits, static idx only
  #pragma unroll
  for (int r = 0; r < 4; ++r)
    #pragma unroll
    for (int wo = 0; wo < 4; ++wo) mwv[r][wo] = 0u;

// ---- pass A body ----
#define PA_BODY(T, BUF, WMID)                                                \
  {                                                                          \
    asm volatile("s_waitcnt vmcnt(4)" ::: "memory");                         \
    __builtin_amdgcn_s_barrier();                                            \
    __builtin_amdgcn_sched_barrier(0);                                       \
    if ((T) + 1 < NT64) { stage_K((T) + 1, (BUF) ^ 1);                       \
                          stage_M((T) + 1, (BUF) ^ 1); }                     \
    f32x4 acc[4];                                                            \
    acc[0] = f32x4{0.f, 0.f, 0.f, 0.f}; acc[1] = f32x4{0.f, 0.f, 0.f, 0.f};  \
    acc[2] = f32x4{0.f, 0.f, 0.f, 0.f}; acc[3] = f32x4{0.f, 0.f, 0.f, 0.f};  \
    qk_tile(&kh_s[BUF][0][0], acc);                                          \
    asm volatile("s_waitcnt vmcnt(" #WMID ")" ::: "memory");                 \
    __builtin_amdgcn_sched_barrier(0);                                       \
    _Pragma("unroll") for (int r = 0; r < 4; ++r) {                          \
      _Pragma("unroll") for (int s = 0; s < 4; ++s) {                        \
        const int mv = m_lds[BUF][rowblk + r][s * 16 + l15];                 \
        mwv[r][(T) >> 3] |= (unsigned)(mv != 0) << (4 * ((T) & 7) + s);      \
        sums[r] += mv ? 0.f : __builtin_amdgcn_exp2f(acc[s][r]);             \
      }                                                                      \
    }                                                                        \
  }

  PA_BODY(0, 0, 6);
  for (int tt = 0; tt < 15; ++tt) {
    PA_BODY(2 * tt + 1, 1, 6);
    PA_BODY(2 * tt + 2, 0, 6);
  }
  PA_BODY(31, 1, 0);

  #pragma unroll
  for (int r = 0; r < 4; ++r) {
    float x = sums[r];
    x += __shfl_xor(x, 1, 64);
    x += __shfl_xor(x, 2, 64);
    x += __shfl_xor(x, 4, 64);
    x += __shfl_xor(x, 8, 64);
    sums[r] = 1.0f / x;
  }

  // ---------------- pass B: weights + PV ----------------
  f32x4 oacc[4];
  #pragma unroll
  for (int s = 0; s < 4; ++s) oacc[s] = f32x4{0.f, 0.f, 0.f, 0.f};

  // prologue: buf0's last pass-A reads were fenced by the PA(31) top barrier.
  stage_K(0, 0);
  stage_V(0, 0);

#define PB_BODY(T, BUF, WAITN)                                               \
  {                                                                          \
    asm volatile("s_waitcnt vmcnt(" #WAITN ")" ::: "memory");                \
    __builtin_amdgcn_s_barrier();                                            \
    __builtin_amdgcn_sched_barrier(0);                                       \
    if ((T) + 1 < NT64) { stage_K((T) + 1, (BUF) ^ 1);                       \
                          stage_V((T) + 1, (BUF) ^ 1); }                     \
    f32x4 acc[4];                                                            \
    acc[0] = f32x4{0.f, 0.f, 0.f, 0.f}; acc[1] = f32x4{0.f, 0.f, 0.f, 0.f};  \
    acc[2] = f32x4{0.f, 0.f, 0.f, 0.f}; acc[3] = f32x4{0.f, 0.f, 0.f, 0.f};  \
    qk_tile(&kh_s[BUF][0][0], acc);                                          \
    const int sh0 = 4 * ((T) & 7);                                           \
    float* wbase = out_w + mofs + (size_t)(T) * 64;                          \
    _Pragma("unroll") for (int r = 0; r < 4; ++r) {                          \
      const unsigned mword = mwv[r][(T) >> 3];                               \
      const int row = (lq << 2) + r;                                         \
      _Pragma("unroll") for (int s = 0; s < 4; ++s) {                        \
        const int m = (int)((mword >> (sh0 + s)) & 1u);                      \
        const float e = m ? 0.f : __builtin_amdgcn_exp2f(acc[s][r]);         \
        const float wn = e * sums[r];                                        \
        wbase[(size_t)r * S_LEN + s * 16] = wn;                              \
        const int chunk = ((s << 1) | (l15 >> 3)) ^ (row & 7);               \
        p_lds[w][row][(chunk << 3) | (l15 & 7)] = f2bf(wn);                  \
      }                                                                      \
    }                                                                        \
    __builtin_amdgcn_wave_barrier();                                         \
    _Pragma("unroll") for (int c = 0; c < 2; ++c) {                          \
      const bf16x8 pa = *(const bf16x8*)                                     \
          &p_lds[w][l15][((((c << 2) | lq)) ^ (l15 & 7)) << 3];              \
      _Pragma("unroll") for (int s = 0; s < 4; ++s) {                        \
        const int off = (s * 16 + l15) * 64 +                                \
                        ((((c << 2) | lq) ^ (l15 & 7)) << 3);                \
        const bf16x8 vb = *(const bf16x8*)(&vt_s[BUF][0][0] + off);          \
        oacc[s] = __builtin_amdgcn_mfma_f32_16x16x32_bf16(pa, vb, oacc[s],   \
                                                          0, 0, 0);          \
      }                                                                      \
    }                                                                        \
    __builtin_amdgcn_wave_barrier();                                         \
  }

  PB_BODY(0, 0, 0);
  for (int tt = 0; tt < 15; ++tt) {
    PB_BODY(2 * tt + 1, 1, 16);
    PB_BODY(2 * tt + 2, 0, 16);
  }
  PB_BODY(31, 1, 16);

  #pragma unroll
  for (int s = 0; s < 4; ++s) {
    #pragma unroll
    for (int r = 0; r < 4; ++r) {
      out_o[oofs + (size_t)r * DK + s * 16] = oacc[s][r];
    }
  }
#undef PA_BODY
#undef PB_BODY
}

// ---------------------------------------------------------------------------
extern "C" void kernel_launch(void* const* d_in, const int* in_sizes, int n_in,
                              void* d_out, int out_size, void* d_ws, size_t ws_size,
                              hipStream_t stream) {
  (void)in_sizes; (void)n_in; (void)out_size; (void)ws_size;
  const float* q = (const float*)d_in[0];
  const float* k = (const float*)d_in[1];
  const float* v = (const float*)d_in[2];
  const int* mask = (const int*)d_in[3];      // bool_ -> int32

  float* out_o = (float*)d_out;               // [B,H,S,D] fp32
  float* out_w = out_o + (size_t)O_ELEMS;     // [B,H,S,S] fp32

  // workspace: K bf16 (16.8 MB) + V_t bf16 (16.8 MB)
  unsigned short* k_hi = (unsigned short*)d_ws;
  unsigned short* v_t  = k_hi + (size_t)O_ELEMS;

  cvt_k_kernel<<<8192, 256, 0, stream>>>(k, k_hi);
  transpose_v_kernel<<<2048, 256, 0, stream>>>(v, v_t);
  attn_main<<<2048, 256, 0, stream>>>(q, mask, k_hi, v_t, out_o, out_w);
}

// Round 11
// 589.869 us; speedup vs baseline: 1.8748x; 1.1280x over previous
//
#include <hip/hip_runtime.h>
#include <hip/hip_bf16.h>

// Problem constants (B=4, H=16, S=2048, D=64, fp32).
#define S_LEN 2048
#define DK    64
#define NT64  32                   // number of 64-wide k-tiles
#define O_ELEMS (4 * 16 * 2048 * 64)       // 8388608 = B*H*S*D

typedef float f32x4  __attribute__((ext_vector_type(4)));
typedef short bf16x8 __attribute__((ext_vector_type(8)));

static __device__ __forceinline__ unsigned short f2bf(float f) {
  unsigned int u = __builtin_bit_cast(unsigned int, f);
  u += 0x7fffu + ((u >> 16) & 1u);
  return (unsigned short)(u >> 16);
}

// async global->LDS, 16B per lane; LDS dest = wave-uniform base + lane*16
static __device__ __forceinline__ void gload_lds16(const void* g, void* l) {
  __builtin_amdgcn_global_load_lds(
      (const __attribute__((address_space(1))) unsigned int*)g,
      (__attribute__((address_space(3))) unsigned int*)l, 16, 0, 0);
}

// ---------------------------------------------------------------------------
// K fp32 -> bf16 (plain round-to-nearest). grid 8192 x 256.
__global__ __launch_bounds__(256) void cvt_k_kernel(
    const float* __restrict__ k, unsigned short* __restrict__ k_hi) {
  int i = blockIdx.x * 256 + threadIdx.x;
  float4 v = ((const float4*)k)[i];
  ushort4 h;
  h.x = f2bf(v.x); h.y = f2bf(v.y); h.z = f2bf(v.z); h.w = f2bf(v.w);
  ((ushort4*)k_hi)[i] = h;
}

// ---------------------------------------------------------------------------
// V [bh][j][d] fp32 -> V_t [bh][d][j] bf16. grid 2048.
__global__ __launch_bounds__(256) void transpose_v_kernel(
    const float* __restrict__ v, unsigned short* __restrict__ v_t) {
  __shared__ float tile[64][65];
  const int b  = blockIdx.x;
  const int bh = b >> 5;
  const int j0 = (b & 31) << 6;
  const int t  = threadIdx.x;
  #pragma unroll
  for (int i = 0; i < 4; ++i) {
    int flat = i * 256 + t;
    int jl   = flat >> 4;
    int f4   = flat & 15;
    float4 x = *(const float4*)(v + ((size_t)bh * S_LEN + j0 + jl) * DK + f4 * 4);
    tile[jl][f4 * 4 + 0] = x.x;
    tile[jl][f4 * 4 + 1] = x.y;
    tile[jl][f4 * 4 + 2] = x.z;
    tile[jl][f4 * 4 + 3] = x.w;
  }
  __syncthreads();
  #pragma unroll
  for (int i = 0; i < 4; ++i) {
    int flat = i * 256 + t;
    int d    = flat >> 4;
    int jg   = (flat & 15) << 2;
    ushort4 o;
    o.x = f2bf(tile[jg + 0][d]);
    o.y = f2bf(tile[jg + 1][d]);
    o.z = f2bf(tile[jg + 2][d]);
    o.w = f2bf(tile[jg + 3][d]);
    *(ushort4*)(v_t + ((size_t)bh * DK + d) * S_LEN + j0 + jg) = o;
  }
}

// ---------------------------------------------------------------------------
// Pass A kernel: QK^T + mask -> inverted row sums + packed mask bits.
// NO manual vmcnt anywhere: __syncthreads double-buffering (R4-proven).
// All VM ops for tile t+1 (K stage DMA + 16 mask loads into the other
// register buffer) are issued at the TOP of iter t, covered by iter t's
// QK+exp compute, and drained by the end-of-iter barrier.
// LDS 16KB. Outputs: bits[thread*16 + r*4+wo] (uint4/thread/row),
// sums_out[id*64+row] = 1/rowsum.
__global__ __launch_bounds__(256, 4) void score_sums(
    const float* __restrict__ q,
    const int* __restrict__ mask,
    const unsigned short* __restrict__ k_hi,
    unsigned int* __restrict__ bits,
    float* __restrict__ sums_out) {
  const int blk = blockIdx.x;                 // 0..2047
  const int id  = ((blk & 7) << 8) | (blk >> 3);  // XCD-contig bh ranges
  const int bh  = id >> 5;
  const int q0  = (id & 31) << 6;
  const int tid = threadIdx.x;
  const int w   = tid >> 6;
  const int ln  = tid & 63;
  const int l15 = ln & 15;
  const int lq  = ln >> 4;

  __shared__ __align__(16) unsigned short kh_s[2][64][64];  // 16 KB

  const int r8  = ln >> 3, c8 = ln & 7;
  const int swz = c8 ^ r8;
  const size_t kst = ((size_t)bh * S_LEN + 16 * w + r8) * DK + ((size_t)swz << 3);
  auto stage_K = [&](int t, int b) {
    gload_lds16(k_hi + kst + (size_t)t * (64 * DK),          &kh_s[b][16 * w][0]);
    gload_lds16(k_hi + kst + (size_t)t * (64 * DK) + 8 * DK, &kh_s[b][16 * w + 8][0]);
  };

  const float* qp = q + ((size_t)bh * S_LEN + q0 + (w << 4) + l15) * DK + (lq << 3);
  const float4 qa0 = *(const float4*)(qp);
  const float4 qb0 = *(const float4*)(qp + 4);
  const float4 qa1 = *(const float4*)(qp + 32);
  const float4 qb1 = *(const float4*)(qp + 36);

  const size_t rowb = (size_t)bh * S_LEN + q0 + (w << 4) + (lq << 2);
  const int* mptr = mask + rowb * S_LEN + l15;

  bf16x8 qh[2];
  {
    const float sc = 0.125f * 1.4426950408889634f;  // fold 1/sqrt(64)*log2(e)
    float vv0[8] = {qa0.x, qa0.y, qa0.z, qa0.w, qb0.x, qb0.y, qb0.z, qb0.w};
    float vv1[8] = {qa1.x, qa1.y, qa1.z, qa1.w, qb1.x, qb1.y, qb1.z, qb1.w};
    #pragma unroll
    for (int i = 0; i < 8; ++i) {
      qh[0][i] = (short)f2bf(vv0[i] * sc);
      qh[1][i] = (short)f2bf(vv1[i] * sc);
    }
  }

  auto qk_tile = [&](const unsigned short* kbase, f32x4 (&acc)[4]) {
    #pragma unroll
    for (int s = 0; s < 4; ++s) {
      #pragma unroll
      for (int c = 0; c < 2; ++c) {
        const int off = (s * 16 + l15) * 64 + ((((c << 2) | lq) ^ (l15 & 7)) << 3);
        const bf16x8 bhf = *(const bf16x8*)(kbase + off);
        acc[s] = __builtin_amdgcn_mfma_f32_16x16x32_bf16(qh[c], bhf, acc[s], 0, 0, 0);
      }
    }
  };

  unsigned mA[16], mB[16];
  float sums[4] = {0.f, 0.f, 0.f, 0.f};
  unsigned mwv[4][4];
  #pragma unroll
  for (int r = 0; r < 4; ++r)
    #pragma unroll
    for (int wo = 0; wo < 4; ++wo) mwv[r][wo] = 0u;

#define LOAD_M(T, M)                                                         \
  _Pragma("unroll") for (int r = 0; r < 4; ++r)                              \
    _Pragma("unroll") for (int s = 0; s < 4; ++s)                            \
      M[r * 4 + s] = (unsigned)mptr[(size_t)r * S_LEN + (T) * 64 + s * 16];

  stage_K(0, 0);
  LOAD_M(0, mA)
  __syncthreads();

#define SA_BODY(T, BUF, MC, MN)                                              \
  {                                                                          \
    if ((T) + 1 < NT64) { stage_K((T) + 1, (BUF) ^ 1); LOAD_M((T) + 1, MN) } \
    f32x4 acc[4];                                                            \
    acc[0] = f32x4{0.f, 0.f, 0.f, 0.f}; acc[1] = f32x4{0.f, 0.f, 0.f, 0.f};  \
    acc[2] = f32x4{0.f, 0.f, 0.f, 0.f}; acc[3] = f32x4{0.f, 0.f, 0.f, 0.f};  \
    qk_tile(&kh_s[BUF][0][0], acc);                                          \
    _Pragma("unroll") for (int r = 0; r < 4; ++r) {                          \
      _Pragma("unroll") for (int s = 0; s < 4; ++s) {                        \
        const unsigned mv = MC[r * 4 + s];                                   \
        mwv[r][(T) >> 3] |= (unsigned)(mv != 0) << (4 * ((T) & 7) + s);      \
        sums[r] += mv ? 0.f : __builtin_amdgcn_exp2f(acc[s][r]);             \
      }                                                                      \
    }                                                                        \
    __syncthreads();                                                         \
  }

  SA_BODY(0, 0, mA, mB)
  for (int tt = 0; tt < 15; ++tt) {
    SA_BODY(2 * tt + 1, 1, mB, mA)
    SA_BODY(2 * tt + 2, 0, mA, mB)
  }
  SA_BODY(31, 1, mB, mA)

  // reduce across the 16 lanes sharing each row; invert; write
  #pragma unroll
  for (int r = 0; r < 4; ++r) {
    float x = sums[r];
    x += __shfl_xor(x, 1, 64);
    x += __shfl_xor(x, 2, 64);
    x += __shfl_xor(x, 4, 64);
    x += __shfl_xor(x, 8, 64);
    if (l15 == 0) sums_out[id * 64 + (w << 4) + (lq << 2) + r] = 1.0f / x;
  }
  unsigned int* bb = bits + ((size_t)id * 256 + tid) * 16;
  #pragma unroll
  for (int r = 0; r < 4; ++r)
    *(uint4*)(bb + 4 * r) = make_uint4(mwv[r][0], mwv[r][1], mwv[r][2], mwv[r][3]);
#undef SA_BODY
#undef LOAD_M
}

// ---------------------------------------------------------------------------
// Pass B kernel: R7's validated pass-B schedule VERBATIM. Mask bits and
// inverted sums come from ws via prologue register loads (drained by
// PB_BODY(0)'s vmcnt(0); no new in-loop VM ops -> R7's counted-vmcnt
// contract is preserved exactly: steady top vmcnt(16) = stage K/V(T) 4
// oldest retired, stores(T-1) 16 may fly).
__global__ __launch_bounds__(256, 4) void attn_pv(
    const float* __restrict__ q,
    const unsigned int* __restrict__ bits,
    const float* __restrict__ sums_in,
    const unsigned short* __restrict__ k_hi,
    const unsigned short* __restrict__ v_t,
    float* __restrict__ out_o,
    float* __restrict__ out_w) {
  const int blk = blockIdx.x;
  const int id  = ((blk & 7) << 8) | (blk >> 3);
  const int bh  = id >> 5;
  const int q0  = (id & 31) << 6;
  const int tid = threadIdx.x;
  const int w   = tid >> 6;
  const int ln  = tid & 63;
  const int l15 = ln & 15;
  const int lq  = ln >> 4;

  __shared__ __align__(16) unsigned short kh_s[2][64][64];  // 16 KB
  __shared__ __align__(16) unsigned short vt_s[2][64][64];  // 16 KB
  __shared__ __align__(16) unsigned short p_lds[4][16][64]; //  8 KB

  const int r8  = ln >> 3, c8 = ln & 7;
  const int swz = c8 ^ r8;
  const size_t kst = ((size_t)bh * S_LEN + 16 * w + r8) * DK + ((size_t)swz << 3);
  const size_t vst = ((size_t)bh * DK + 16 * w + r8) * S_LEN + ((size_t)swz << 3);

  auto stage_K = [&](int t, int b) {
    gload_lds16(k_hi + kst + (size_t)t * (64 * DK),          &kh_s[b][16 * w][0]);
    gload_lds16(k_hi + kst + (size_t)t * (64 * DK) + 8 * DK, &kh_s[b][16 * w + 8][0]);
  };
  auto stage_V = [&](int t, int b) {
    gload_lds16(v_t + vst + (size_t)t * 64,             &vt_s[b][16 * w][0]);
    gload_lds16(v_t + vst + (size_t)t * 64 + 8 * S_LEN, &vt_s[b][16 * w + 8][0]);
  };

  // prologue register loads (OLDER than the stage DMA; drained at PB0 vmcnt(0))
  const float* qp = q + ((size_t)bh * S_LEN + q0 + (w << 4) + l15) * DK + (lq << 3);
  const float4 qa0 = *(const float4*)(qp);
  const float4 qb0 = *(const float4*)(qp + 4);
  const float4 qa1 = *(const float4*)(qp + 32);
  const float4 qb1 = *(const float4*)(qp + 36);
  const uint4* bq = (const uint4*)(bits + ((size_t)id * 256 + tid) * 16);
  uint4 mq[4];
  #pragma unroll
  for (int r = 0; r < 4; ++r) mq[r] = bq[r];
  const float* sp = sums_in + id * 64 + (w << 4) + (lq << 2);
  float sums[4] = {sp[0], sp[1], sp[2], sp[3]};   // already inverted

  bf16x8 qh[2];
  {
    const float sc = 0.125f * 1.4426950408889634f;
    float vv0[8] = {qa0.x, qa0.y, qa0.z, qa0.w, qb0.x, qb0.y, qb0.z, qb0.w};
    float vv1[8] = {qa1.x, qa1.y, qa1.z, qa1.w, qb1.x, qb1.y, qb1.z, qb1.w};
    #pragma unroll
    for (int i = 0; i < 8; ++i) {
      qh[0][i] = (short)f2bf(vv0[i] * sc);
      qh[1][i] = (short)f2bf(vv1[i] * sc);
    }
  }

  const size_t rowb = (size_t)bh * S_LEN + q0 + (w << 4) + (lq << 2);
  const size_t mofs = rowb * S_LEN + l15;
  const size_t oofs = rowb * DK + l15;

  auto qk_tile = [&](const unsigned short* kbase, f32x4 (&acc)[4]) {
    #pragma unroll
    for (int s = 0; s < 4; ++s) {
      #pragma unroll
      for (int c = 0; c < 2; ++c) {
        const int off = (s * 16 + l15) * 64 + ((((c << 2) | lq) ^ (l15 & 7)) << 3);
        const bf16x8 bhf = *(const bf16x8*)(kbase + off);
        acc[s] = __builtin_amdgcn_mfma_f32_16x16x32_bf16(qh[c], bhf, acc[s], 0, 0, 0);
      }
    }
  };

  f32x4 oacc[4];
  #pragma unroll
  for (int s = 0; s < 4; ++s) oacc[s] = f32x4{0.f, 0.f, 0.f, 0.f};

  stage_K(0, 0);
  stage_V(0, 0);

#define PB_BODY(T, BUF, WAITN)                                               \
  {                                                                          \
    asm volatile("s_waitcnt vmcnt(" #WAITN ")" ::: "memory");                \
    __builtin_amdgcn_s_barrier();                                            \
    __builtin_amdgcn_sched_barrier(0);                                       \
    if ((T) + 1 < NT64) { stage_K((T) + 1, (BUF) ^ 1);                       \
                          stage_V((T) + 1, (BUF) ^ 1); }                     \
    __builtin_amdgcn_sched_barrier(0);  /* stages pinned before stores */    \
    f32x4 acc[4];                                                            \
    acc[0] = f32x4{0.f, 0.f, 0.f, 0.f}; acc[1] = f32x4{0.f, 0.f, 0.f, 0.f};  \
    acc[2] = f32x4{0.f, 0.f, 0.f, 0.f}; acc[3] = f32x4{0.f, 0.f, 0.f, 0.f};  \
    qk_tile(&kh_s[BUF][0][0], acc);                                          \
    const int wsel = (T) >> 3;                                               \
    const int sh0 = 4 * ((T) & 7);                                           \
    float* wbase = out_w + mofs + (size_t)(T) * 64;                          \
    _Pragma("unroll") for (int r = 0; r < 4; ++r) {                          \
      const unsigned mword = wsel == 0 ? mq[r].x : wsel == 1 ? mq[r].y       \
                           : wsel == 2 ? mq[r].z : mq[r].w;                  \
      const int row = (lq << 2) + r;                                         \
      _Pragma("unroll") for (int s = 0; s < 4; ++s) {                        \
        const int m = (int)((mword >> (sh0 + s)) & 1u);                      \
        const float e = m ? 0.f : __builtin_amdgcn_exp2f(acc[s][r]);         \
        const float wn = e * sums[r];                                        \
        wbase[(size_t)r * S_LEN + s * 16] = wn;                              \
        const int chunk = ((s << 1) | (l15 >> 3)) ^ (row & 7);               \
        p_lds[w][row][(chunk << 3) | (l15 & 7)] = f2bf(wn);                  \
      }                                                                      \
    }                                                                        \
    __builtin_amdgcn_wave_barrier();                                         \
    _Pragma("unroll") for (int c = 0; c < 2; ++c) {                          \
      const bf16x8 pa = *(const bf16x8*)                                     \
          &p_lds[w][l15][((((c << 2) | lq)) ^ (l15 & 7)) << 3];              \
      _Pragma("unroll") for (int s = 0; s < 4; ++s) {                        \
        const int off = (s * 16 + l15) * 64 +                                \
                        ((((c << 2) | lq) ^ (l15 & 7)) << 3);                \
        const bf16x8 vb = *(const bf16x8*)(&vt_s[BUF][0][0] + off);          \
        oacc[s] = __builtin_amdgcn_mfma_f32_16x16x32_bf16(pa, vb, oacc[s],   \
                                                          0, 0, 0);          \
      }                                                                      \
    }                                                                        \
    __builtin_amdgcn_wave_barrier();                                         \
  }

  PB_BODY(0, 0, 0)
  for (int tt = 0; tt < 15; ++tt) {
    PB_BODY(2 * tt + 1, 1, 16)
    PB_BODY(2 * tt + 2, 0, 16)
  }
  PB_BODY(31, 1, 16)

  #pragma unroll
  for (int s = 0; s < 4; ++s) {
    #pragma unroll
    for (int r = 0; r < 4; ++r) {
      out_o[oofs + (size_t)r * DK + s * 16] = oacc[s][r];
    }
  }
#undef PB_BODY
}

// ---------------------------------------------------------------------------
extern "C" void kernel_launch(void* const* d_in, const int* in_sizes, int n_in,
                              void* d_out, int out_size, void* d_ws, size_t ws_size,
                              hipStream_t stream) {
  (void)in_sizes; (void)n_in; (void)out_size; (void)ws_size;
  const float* q = (const float*)d_in[0];
  const float* k = (const float*)d_in[1];
  const float* v = (const float*)d_in[2];
  const int* mask = (const int*)d_in[3];      // bool_ -> int32

  float* out_o = (float*)d_out;               // [B,H,S,D] fp32
  float* out_w = out_o + (size_t)O_ELEMS;     // [B,H,S,S] fp32

  // workspace: K bf16 16.8MB + V_t bf16 16.8MB + bits 33.6MB + sums 0.5MB
  unsigned short* k_hi = (unsigned short*)d_ws;
  unsigned short* v_t  = k_hi + (size_t)O_ELEMS;
  unsigned int*   bits = (unsigned int*)(v_t + (size_t)O_ELEMS);
  float*          sums = (float*)(bits + (size_t)2048 * 256 * 16);

  cvt_k_kernel<<<8192, 256, 0, stream>>>(k, k_hi);
  transpose_v_kernel<<<2048, 256, 0, stream>>>(v, v_t);
  score_sums<<<2048, 256, 0, stream>>>(q, mask, k_hi, bits, sums);
  attn_pv<<<2048, 256, 0, stream>>>(q, bits, sums, k_hi, v_t, out_o, out_w);
}